// Round 1
// baseline (166.245 us; speedup 1.0000x reference)
//
#include <hip/hip_runtime.h>
#include <math.h>

#define BATCH 128
#define IH    128
#define IW    512
#define CH    3
#define OH    64
#define OW    256
#define KCP   20
#define KP3   23   // K + 3

struct InvMat { float v[KP3 * KP3]; };

// ---------------------------------------------------------------------------
// Kernel 1: per-batch TPS coefficients  T[b] = INV_DELTA @ [ctrl[b]; 0_{3x2}]
// grid = BATCH blocks x 64 threads. Only rows j<20 of Cp0 are nonzero.
// ---------------------------------------------------------------------------
__global__ __launch_bounds__(64) void tps_T_kernel(InvMat inv,
                                                   const float* __restrict__ ctrl,
                                                   float* __restrict__ T) {
    int b = blockIdx.x;
    __shared__ float sc[KCP * 2];
    int t = threadIdx.x;
    if (t < KCP * 2) sc[t] = ctrl[b * KCP * 2 + t];
    __syncthreads();
    if (t < KP3 * 2) {
        int i = t >> 1, c = t & 1;
        double acc = 0.0;
        #pragma unroll
        for (int j = 0; j < KCP; ++j)
            acc += (double)inv.v[i * KP3 + j] * (double)sc[j * 2 + c];
        T[b * (KP3 * 2) + i * 2 + c] = (float)acc;
    }
}

// ---------------------------------------------------------------------------
// Kernel 2: fused grid-gen + bilinear sampling.
// One block per output row (b, y); thread x = output column.
// ---------------------------------------------------------------------------
__global__ __launch_bounds__(256) void tps_sample_kernel(const float* __restrict__ X,
                                                         const float* __restrict__ T,
                                                         float* __restrict__ out) {
    int bid = blockIdx.x;            // b * OH + y
    int b = bid >> 6;                // OH = 64
    int y = bid & (OH - 1);
    int x = threadIdx.x;

    __shared__ float sT[KP3 * 2];
    if (x < KP3 * 2) sT[x] = T[b * (KP3 * 2) + x];
    __syncthreads();

    float gx = ((float)x + 0.5f) * (1.0f / OW);
    float gy = ((float)y + 0.5f) * (1.0f / OH);

    float px = sT[0] + gx * sT[2] + gy * sT[4];
    float py = sT[1] + gx * sT[3] + gy * sT[5];

    #pragma unroll
    for (int i = 0; i < KCP; ++i) {
        float cx = 0.05f + 0.1f * (float)(i % 10);
        float cy = (i < 10) ? 0.05f : 0.95f;
        float dx = gx - cx, dy = gy - cy;
        float d2 = dx * dx + dy * dy;
        // d^2 * log(d + 1e-6) ~= 0.5 * d^2 * log(d^2); min d ~ 4.7e-3 so eps
        // contributes < 1e-8 absolute — far below tolerance.
        float r = d2 * (0.5f * __logf(d2));
        px += r * sT[(3 + i) * 2 + 0];
        py += r * sT[(3 + i) * 2 + 1];
    }

    float Gx = fminf(fmaxf((float)IW * px, 0.0f), (float)(IW - 2));
    float Gy = fminf(fmaxf((float)IH * py, 0.0f), (float)(IH - 2));
    float fx0 = floorf(Gx), fy0 = floorf(Gy);
    int x0 = (int)fx0, y0 = (int)fy0;
    float fx = Gx - fx0, fy = Gy - fy0;

    float w00 = (1.0f - fx) * (1.0f - fy);
    float w10 = fx * (1.0f - fy);
    float w01 = (1.0f - fx) * fy;
    float w11 = fx * fy;

    const float* p00 = X + (((size_t)b * IH + y0) * IW + x0) * CH;  // (y0,x0),(y0,x1)
    const float* p01 = p00 + (size_t)IW * CH;                        // (y1,x0),(y1,x1)

    float o0 = w00 * p00[0] + w10 * p00[3] + w01 * p01[0] + w11 * p01[3];
    float o1 = w00 * p00[1] + w10 * p00[4] + w01 * p01[1] + w11 * p01[4];
    float o2 = w00 * p00[2] + w10 * p00[5] + w01 * p01[2] + w11 * p01[5];

    float* o = out + ((size_t)bid * OW + x) * CH;
    o[0] = o0; o[1] = o1; o[2] = o2;
}

// ---------------------------------------------------------------------------
// Host
// ---------------------------------------------------------------------------
extern "C" void kernel_launch(void* const* d_in, const int* in_sizes, int n_in,
                              void* d_out, int out_size, void* d_ws, size_t ws_size,
                              hipStream_t stream) {
    const float* X    = (const float*)d_in[0];
    const float* ctrl = (const float*)d_in[1];
    float* out = (float*)d_out;
    float* T   = (float*)d_ws;   // BATCH * 46 floats = 23552 B

    // ---- host-side: control points + inverse delta matrix (float64) ----
    double C[KCP][2];
    for (int j = 0; j < 10; ++j) {
        C[j][0]      = 0.05 + 0.1 * j;  C[j][1]      = 0.05;
        C[10 + j][0] = 0.05 + 0.1 * j;  C[10 + j][1] = 0.95;
    }

    double A[KP3][2 * KP3];
    for (int i = 0; i < KP3; ++i)
        for (int j = 0; j < 2 * KP3; ++j) A[i][j] = 0.0;

    for (int i = 0; i < KCP; ++i) {
        A[i][0] = 1.0; A[i][1] = C[i][0]; A[i][2] = C[i][1];
        for (int j = 0; j < KCP; ++j) {
            if (i == j) { A[i][3 + j] = 0.0; continue; }
            double dx = C[i][0] - C[j][0], dy = C[i][1] - C[j][1];
            double r2 = dx * dx + dy * dy;
            A[i][3 + j] = 0.5 * r2 * log(r2);   // r^2 * log(r)
        }
    }
    for (int j = 0; j < KCP; ++j) {
        A[KCP + 0][3 + j] = C[j][0];
        A[KCP + 1][3 + j] = C[j][1];
        A[KCP + 2][3 + j] = 1.0;
    }
    for (int i = 0; i < KP3; ++i) A[i][KP3 + i] = 1.0;   // augment identity

    // Gauss-Jordan with partial pivoting (float64, host)
    for (int k = 0; k < KP3; ++k) {
        int p = k; double best = fabs(A[k][k]);
        for (int i = k + 1; i < KP3; ++i)
            if (fabs(A[i][k]) > best) { best = fabs(A[i][k]); p = i; }
        if (p != k)
            for (int j = 0; j < 2 * KP3; ++j) { double t = A[k][j]; A[k][j] = A[p][j]; A[p][j] = t; }
        double pv = A[k][k];
        for (int j = 0; j < 2 * KP3; ++j) A[k][j] /= pv;
        for (int i = 0; i < KP3; ++i) {
            if (i == k) continue;
            double m = A[i][k];
            if (m == 0.0) continue;
            for (int j = 0; j < 2 * KP3; ++j) A[i][j] -= m * A[k][j];
        }
    }

    InvMat inv;
    for (int i = 0; i < KP3; ++i)
        for (int j = 0; j < KP3; ++j)
            inv.v[i * KP3 + j] = (float)A[i][KP3 + j];

    // ---- device ----
    tps_T_kernel<<<BATCH, 64, 0, stream>>>(inv, ctrl, T);
    tps_sample_kernel<<<BATCH * OH, 256, 0, stream>>>(X, T, out);
}

// Round 2
// 162.763 us; speedup vs baseline: 1.0214x; 1.0214x over previous
//
#include <hip/hip_runtime.h>
#include <math.h>

#define BATCH 128
#define IH    128
#define IW    512
#define CH    3
#define OH    64
#define OW    256
#define KCP   20
#define KP3   23   // K + 3

struct InvMat { float v[KP3 * KP3]; };

// ---------------------------------------------------------------------------
// Fused kernel: per-block TPS coefficient solve (tiny) + grid-gen + bilinear
// sampling. One block per output row (b, y); thread x = output column.
// Block-id swizzle clusters all 64 rows of an image on one XCD for L2 reuse.
// ---------------------------------------------------------------------------
__global__ __launch_bounds__(256) void tps_fused_kernel(InvMat inv,
                                                        const float* __restrict__ ctrl,
                                                        const float* __restrict__ X,
                                                        float* __restrict__ out) {
    int bid = blockIdx.x;                 // = ((b>>3)*64 + y)*8 + (b&7)
    int xcd  = bid & 7;
    int slot = bid >> 3;
    int y = slot & (OH - 1);
    int b = ((slot >> 6) << 3) | xcd;

    __shared__ float sc[KCP * 2];
    __shared__ float sT[KP3 * 2];
    int x = threadIdx.x;

    if (x < KCP * 2) sc[x] = ctrl[b * KCP * 2 + x];
    __syncthreads();
    if (x < KP3 * 2) {                    // T = INV_DELTA @ [ctrl; 0]
        int i = x >> 1, c = x & 1;
        float acc = 0.0f;
        #pragma unroll
        for (int j = 0; j < KCP; ++j)
            acc += inv.v[i * KP3 + j] * sc[j * 2 + c];
        sT[x] = acc;
    }
    __syncthreads();

    float gx = ((float)x + 0.5f) * (1.0f / OW);
    float gy = ((float)y + 0.5f) * (1.0f / OH);

    float px = sT[0] + gx * sT[2] + gy * sT[4];
    float py = sT[1] + gx * sT[3] + gy * sT[5];

    #pragma unroll
    for (int i = 0; i < KCP; ++i) {
        float cx = 0.05f + 0.1f * (float)(i % 10);
        float cy = (i < 10) ? 0.05f : 0.95f;
        float dx = gx - cx, dy = gy - cy;
        float d2 = dx * dx + dy * dy;
        // d^2 * log(d + 1e-6) ~= 0.5 * d^2 * log(d^2); min d ~ 4.7e-3.
        float r = d2 * (0.5f * __logf(d2));
        px += r * sT[(3 + i) * 2 + 0];
        py += r * sT[(3 + i) * 2 + 1];
    }

    float Gx = fminf(fmaxf((float)IW * px, 0.0f), (float)(IW - 2));
    float Gy = fminf(fmaxf((float)IH * py, 0.0f), (float)(IH - 2));
    float fx0 = floorf(Gx), fy0 = floorf(Gy);
    int x0 = (int)fx0, y0 = (int)fy0;
    float fx = Gx - fx0, fy = Gy - fy0;

    float w00 = (1.0f - fx) * (1.0f - fy);
    float w10 = fx * (1.0f - fy);
    float w01 = (1.0f - fx) * fy;
    float w11 = fx * fy;

    const float* p00 = X + (((size_t)b * IH + y0) * IW + x0) * CH;  // (y0,x0),(y0,x1)
    const float* p01 = p00 + (size_t)IW * CH;                        // (y1,x0),(y1,x1)

    float o0 = w00 * p00[0] + w10 * p00[3] + w01 * p01[0] + w11 * p01[3];
    float o1 = w00 * p00[1] + w10 * p00[4] + w01 * p01[1] + w11 * p01[4];
    float o2 = w00 * p00[2] + w10 * p00[5] + w01 * p01[2] + w11 * p01[5];

    // out is write-once — nontemporal keeps it from evicting X in L2.
    float* o = out + (((size_t)b * OH + y) * OW + x) * CH;
    __builtin_nontemporal_store(o0, o + 0);
    __builtin_nontemporal_store(o1, o + 1);
    __builtin_nontemporal_store(o2, o + 2);
}

// ---------------------------------------------------------------------------
// Host
// ---------------------------------------------------------------------------
extern "C" void kernel_launch(void* const* d_in, const int* in_sizes, int n_in,
                              void* d_out, int out_size, void* d_ws, size_t ws_size,
                              hipStream_t stream) {
    const float* X    = (const float*)d_in[0];
    const float* ctrl = (const float*)d_in[1];
    float* out = (float*)d_out;

    // ---- host-side: control points + inverse delta matrix (float64) ----
    double C[KCP][2];
    for (int j = 0; j < 10; ++j) {
        C[j][0]      = 0.05 + 0.1 * j;  C[j][1]      = 0.05;
        C[10 + j][0] = 0.05 + 0.1 * j;  C[10 + j][1] = 0.95;
    }

    double A[KP3][2 * KP3];
    for (int i = 0; i < KP3; ++i)
        for (int j = 0; j < 2 * KP3; ++j) A[i][j] = 0.0;

    for (int i = 0; i < KCP; ++i) {
        A[i][0] = 1.0; A[i][1] = C[i][0]; A[i][2] = C[i][1];
        for (int j = 0; j < KCP; ++j) {
            if (i == j) { A[i][3 + j] = 0.0; continue; }
            double dx = C[i][0] - C[j][0], dy = C[i][1] - C[j][1];
            double r2 = dx * dx + dy * dy;
            A[i][3 + j] = 0.5 * r2 * log(r2);   // r^2 * log(r)
        }
    }
    for (int j = 0; j < KCP; ++j) {
        A[KCP + 0][3 + j] = C[j][0];
        A[KCP + 1][3 + j] = C[j][1];
        A[KCP + 2][3 + j] = 1.0;
    }
    for (int i = 0; i < KP3; ++i) A[i][KP3 + i] = 1.0;   // augment identity

    // Gauss-Jordan with partial pivoting (float64, host)
    for (int k = 0; k < KP3; ++k) {
        int p = k; double best = fabs(A[k][k]);
        for (int i = k + 1; i < KP3; ++i)
            if (fabs(A[i][k]) > best) { best = fabs(A[i][k]); p = i; }
        if (p != k)
            for (int j = 0; j < 2 * KP3; ++j) { double t = A[k][j]; A[k][j] = A[p][j]; A[p][j] = t; }
        double pv = A[k][k];
        for (int j = 0; j < 2 * KP3; ++j) A[k][j] /= pv;
        for (int i = 0; i < KP3; ++i) {
            if (i == k) continue;
            double m = A[i][k];
            if (m == 0.0) continue;
            for (int j = 0; j < 2 * KP3; ++j) A[i][j] -= m * A[k][j];
        }
    }

    InvMat inv;
    for (int i = 0; i < KP3; ++i)
        for (int j = 0; j < KP3; ++j)
            inv.v[i * KP3 + j] = (float)A[i][KP3 + j];

    // ---- device: single fused kernel ----
    tps_fused_kernel<<<BATCH * OH, 256, 0, stream>>>(inv, ctrl, X, out);
}

// Round 3
// 162.548 us; speedup vs baseline: 1.0227x; 1.0013x over previous
//
#include <hip/hip_runtime.h>
#include <math.h>

#define BATCH 128
#define IH    128
#define IW    512
#define CH    3
#define OH    64
#define OW    256
#define KCP   20
#define KP3   23   // K + 3

struct InvMat { float v[KP3 * KP3]; };

// ---------------------------------------------------------------------------
// Fused kernel: per-block TPS coefficient solve (tiny) + grid-gen + bilinear
// sampling. One block per output row (b, y); thread x = output column.
// Block-id swizzle clusters all 64 rows of an image on one XCD for L2 reuse.
// ---------------------------------------------------------------------------
__global__ __launch_bounds__(256) void tps_fused_kernel(InvMat inv,
                                                        const float* __restrict__ ctrl,
                                                        const float* __restrict__ X,
                                                        float* __restrict__ out) {
    int bid = blockIdx.x;                 // = ((b>>3)*64 + y)*8 + (b&7)
    int xcd  = bid & 7;
    int slot = bid >> 3;
    int y = slot & (OH - 1);
    int b = ((slot >> 6) << 3) | xcd;

    __shared__ float sc[KCP * 2];
    __shared__ float sT[KP3 * 2];
    int x = threadIdx.x;

    if (x < KCP * 2) sc[x] = ctrl[b * KCP * 2 + x];
    __syncthreads();
    if (x < KP3 * 2) {                    // T = INV_DELTA @ [ctrl; 0]
        int i = x >> 1, c = x & 1;
        float acc = 0.0f;
        #pragma unroll
        for (int j = 0; j < KCP; ++j)
            acc += inv.v[i * KP3 + j] * sc[j * 2 + c];
        sT[x] = acc;
    }
    __syncthreads();

    float gx = ((float)x + 0.5f) * (1.0f / OW);
    float gy = ((float)y + 0.5f) * (1.0f / OH);

    float px = sT[0] + gx * sT[2] + gy * sT[4];
    float py = sT[1] + gx * sT[3] + gy * sT[5];

    #pragma unroll
    for (int i = 0; i < KCP; ++i) {
        float cx = 0.05f + 0.1f * (float)(i % 10);
        float cy = (i < 10) ? 0.05f : 0.95f;
        float dx = gx - cx, dy = gy - cy;
        float d2 = dx * dx + dy * dy;
        // d^2 * log(d + 1e-6) ~= 0.5 * d^2 * log(d^2); min d ~ 4.7e-3.
        float r = d2 * (0.5f * __logf(d2));
        px += r * sT[(3 + i) * 2 + 0];
        py += r * sT[(3 + i) * 2 + 1];
    }

    float Gx = fminf(fmaxf((float)IW * px, 0.0f), (float)(IW - 2));
    float Gy = fminf(fmaxf((float)IH * py, 0.0f), (float)(IH - 2));
    float fx0 = floorf(Gx), fy0 = floorf(Gy);
    int x0 = (int)fx0, y0 = (int)fy0;
    float fx = Gx - fx0, fy = Gy - fy0;

    float w00 = (1.0f - fx) * (1.0f - fy);
    float w10 = fx * (1.0f - fy);
    float w01 = (1.0f - fx) * fy;
    float w11 = fx * fy;

    const float* p00 = X + (((size_t)b * IH + y0) * IW + x0) * CH;  // (y0,x0),(y0,x1)
    const float* p01 = p00 + (size_t)IW * CH;                        // (y1,x0),(y1,x1)

    // Each row segment is 24 contiguous bytes (pixels x0,x1 x 3ch), align 4.
    // memcpy lets the compiler emit wide unaligned loads (dwordx4+dwordx2)
    // instead of 6 scalar dwords per row. Exactly in-bounds (x0<=510,y0<=126).
    float r0[6], r1[6];
    __builtin_memcpy(r0, p00, 24);
    __builtin_memcpy(r1, p01, 24);

    float o0 = w00 * r0[0] + w10 * r0[3] + w01 * r1[0] + w11 * r1[3];
    float o1 = w00 * r0[1] + w10 * r0[4] + w01 * r1[1] + w11 * r1[4];
    float o2 = w00 * r0[2] + w10 * r0[5] + w01 * r1[2] + w11 * r1[5];

    // out is write-once — nontemporal keeps it from evicting X in L2.
    float* o = out + (((size_t)b * OH + y) * OW + x) * CH;
    __builtin_nontemporal_store(o0, o + 0);
    __builtin_nontemporal_store(o1, o + 1);
    __builtin_nontemporal_store(o2, o + 2);
}

// ---------------------------------------------------------------------------
// Host
// ---------------------------------------------------------------------------
extern "C" void kernel_launch(void* const* d_in, const int* in_sizes, int n_in,
                              void* d_out, int out_size, void* d_ws, size_t ws_size,
                              hipStream_t stream) {
    const float* X    = (const float*)d_in[0];
    const float* ctrl = (const float*)d_in[1];
    float* out = (float*)d_out;

    // ---- host-side: control points + inverse delta matrix (float64) ----
    double C[KCP][2];
    for (int j = 0; j < 10; ++j) {
        C[j][0]      = 0.05 + 0.1 * j;  C[j][1]      = 0.05;
        C[10 + j][0] = 0.05 + 0.1 * j;  C[10 + j][1] = 0.95;
    }

    double A[KP3][2 * KP3];
    for (int i = 0; i < KP3; ++i)
        for (int j = 0; j < 2 * KP3; ++j) A[i][j] = 0.0;

    for (int i = 0; i < KCP; ++i) {
        A[i][0] = 1.0; A[i][1] = C[i][0]; A[i][2] = C[i][1];
        for (int j = 0; j < KCP; ++j) {
            if (i == j) { A[i][3 + j] = 0.0; continue; }
            double dx = C[i][0] - C[j][0], dy = C[i][1] - C[j][1];
            double r2 = dx * dx + dy * dy;
            A[i][3 + j] = 0.5 * r2 * log(r2);   // r^2 * log(r)
        }
    }
    for (int j = 0; j < KCP; ++j) {
        A[KCP + 0][3 + j] = C[j][0];
        A[KCP + 1][3 + j] = C[j][1];
        A[KCP + 2][3 + j] = 1.0;
    }
    for (int i = 0; i < KP3; ++i) A[i][KP3 + i] = 1.0;   // augment identity

    // Gauss-Jordan with partial pivoting (float64, host)
    for (int k = 0; k < KP3; ++k) {
        int p = k; double best = fabs(A[k][k]);
        for (int i = k + 1; i < KP3; ++i)
            if (fabs(A[i][k]) > best) { best = fabs(A[i][k]); p = i; }
        if (p != k)
            for (int j = 0; j < 2 * KP3; ++j) { double t = A[k][j]; A[k][j] = A[p][j]; A[p][j] = t; }
        double pv = A[k][k];
        for (int j = 0; j < 2 * KP3; ++j) A[k][j] /= pv;
        for (int i = 0; i < KP3; ++i) {
            if (i == k) continue;
            double m = A[i][k];
            if (m == 0.0) continue;
            for (int j = 0; j < 2 * KP3; ++j) A[i][j] -= m * A[k][j];
        }
    }

    InvMat inv;
    for (int i = 0; i < KP3; ++i)
        for (int j = 0; j < KP3; ++j)
            inv.v[i * KP3 + j] = (float)A[i][KP3 + j];

    // ---- device: single fused kernel ----
    tps_fused_kernel<<<BATCH * OH, 256, 0, stream>>>(inv, ctrl, X, out);
}